// Round 1
// baseline (626.122 us; speedup 1.0000x reference)
//
#include <hip/hip_runtime.h>

// Problem constants
#define T_FRAMES 16384
#define KDIM 4096
#define STARTS 62
#define STOPS 63
#define NEGV (-10000.0f)

// Chunked-Viterbi (max-plus coalescence: any init washes out up to an additive
// constant, argmax-invariant). Chunks whose burn-in would start at t<=0 run
// from the TRUE init -> exact. BURN=48 >> observed coalescence (<~30).
#define CHUNK_L 16
#define BURN 48
#define NCHUNK (T_FRAMES / CHUNK_L)   // 1024

// Backtrace chunking: 128 chunks x 128 steps.
#define BT_S 128
#define BT_C (T_FRAMES / BT_S)        // 128

#define SPIN_BOUND (1 << 20)          // ~50ms worst-case; real waits are us-scale

typedef __attribute__((ext_vector_type(8))) short s16x8;
typedef __attribute__((ext_vector_type(4))) float f32x4;

__device__ __forceinline__ float lane_bcast(float v, int l) {
  return __uint_as_float(__builtin_amdgcn_readlane(__float_as_uint(v), l));
}

// fp32 -> bf16 RTNE
__device__ __forceinline__ unsigned short f2bf(float f) {
  unsigned u = __float_as_uint(f);
  return (unsigned short)((u + 0x7FFFu + ((u >> 16) & 1u)) >> 16);
}

// ---------------------------------------------------------------------------
// K0: W fp32 [64][4096] -> bf16; also zeroes the sync flags (re-run every
// graph replay, so poison between iterations is harmless).
// ---------------------------------------------------------------------------
__global__ __launch_bounds__(256) void wconv_kernel(
    const float* __restrict__ W, unsigned short* __restrict__ wbf,
    unsigned int* __restrict__ flags) {
  if (blockIdx.x == 0) {
    for (int j = threadIdx.x; j < NCHUNK + 2; j += 256) flags[j] = 0u;
  }
  int i = (blockIdx.x * 256 + threadIdx.x) * 4;
  float4 v = *(const float4*)&W[i];
  ushort4 o;
  o.x = f2bf(v.x); o.y = f2bf(v.y); o.z = f2bf(v.z); o.w = f2bf(v.w);
  *(ushort4*)&wbf[i] = o;
}

// ---------------------------------------------------------------------------
// K1+K2 fused: block b computes feats rows of chunk c (XCD-swizzled so chunks
// c-3..c are produced on the SAME XCD -> L2-local handoff), flags completion
// (device-scope release), then wave 0 runs Viterbi chunk c, spin-waiting on
// lower-chunk flags only (deadlock-free: every block flags before any wait).
// Recorded-phase feats are read from LDS (this block just computed them).
// ---------------------------------------------------------------------------
__global__ __launch_bounds__(256, 4) void gemm_vit_kernel(
    const float* __restrict__ video, const unsigned short* __restrict__ wbf,
    const float* __restrict__ bias, const float* __restrict__ trans,
    float* __restrict__ feats, unsigned char* __restrict__ bptr,
    float* __restrict__ lastfv, unsigned int* __restrict__ flags) {
  __shared__ float red[4 * 16 * 68];
  __shared__ float fl[16 * 64];
  const int tid = threadIdx.x;
  const int wave = tid >> 6, lane = tid & 63;
  const int col = lane & 15, quad = lane >> 4;
  // chunk swizzle: XCD x (= blockIdx%8 round-robin) owns chunks [x*128,(x+1)*128)
  const int c = ((blockIdx.x & 7) << 7) | (blockIdx.x >> 3);
  const int m0 = c * 16;

  const float* aptr = video + (size_t)(m0 + col) * KDIM + quad * 8;
  const unsigned short* bptr0 = wbf + (size_t)col * KDIM + quad * 8;

  f32x4 acc[4];
#pragma unroll
  for (int nt = 0; nt < 4; ++nt) acc[nt] = (f32x4){0.f, 0.f, 0.f, 0.f};

  const int kbase = wave * (KDIM / 4);
#pragma unroll 2
  for (int kc = kbase; kc < kbase + KDIM / 4; kc += 32) {
    float4 a0 = *(const float4*)(aptr + kc);
    float4 a1 = *(const float4*)(aptr + kc + 4);
    s16x8 bf[4];
#pragma unroll
    for (int nt = 0; nt < 4; ++nt)
      bf[nt] = *(const s16x8*)(bptr0 + (size_t)nt * 16 * KDIM + kc);
    s16x8 af;
    af[0] = (short)f2bf(a0.x); af[1] = (short)f2bf(a0.y);
    af[2] = (short)f2bf(a0.z); af[3] = (short)f2bf(a0.w);
    af[4] = (short)f2bf(a1.x); af[5] = (short)f2bf(a1.y);
    af[6] = (short)f2bf(a1.z); af[7] = (short)f2bf(a1.w);
#pragma unroll
    for (int nt = 0; nt < 4; ++nt)
      acc[nt] = __builtin_amdgcn_mfma_f32_16x16x32_bf16(af, bf[nt], acc[nt], 0, 0, 0);
  }

#pragma unroll
  for (int nt = 0; nt < 4; ++nt)
#pragma unroll
    for (int r = 0; r < 4; ++r) {
      int m = quad * 4 + r, n = nt * 16 + col;
      red[wave * 1088 + m * 68 + n] = acc[nt][r];
    }
  __syncthreads();
  {
    int m = tid >> 4, n = (tid & 15) * 4;
    float4 s = *(const float4*)&red[0 * 1088 + m * 68 + n];
    float4 s1 = *(const float4*)&red[1 * 1088 + m * 68 + n];
    float4 s2 = *(const float4*)&red[2 * 1088 + m * 68 + n];
    float4 s3 = *(const float4*)&red[3 * 1088 + m * 68 + n];
    float4 bb = *(const float4*)&bias[n];
    float4 r;
    r.x = fmaxf(s.x + s1.x + s2.x + s3.x + bb.x, 0.f);
    r.y = fmaxf(s.y + s1.y + s2.y + s3.y + bb.y, 0.f);
    r.z = fmaxf(s.z + s1.z + s2.z + s3.z + bb.z, 0.f);
    r.w = fmaxf(s.w + s1.w + s2.w + s3.w + bb.w, 0.f);
    *(float4*)&feats[(size_t)(m0 + m) * 64 + n] = r;
    *(float4*)&fl[m * 64 + n] = r;
  }
  __syncthreads();  // drains vmcnt per-wave: feats stores are in cache hierarchy
  if (tid == 0) {
    __threadfence();  // push to device coherence point
    __hip_atomic_store(&flags[c], 1u, __ATOMIC_RELEASE, __HIP_MEMORY_SCOPE_AGENT);
  }
  if (wave != 0) return;

  // ---- Viterbi chunk c (wave 0 only) ----
  float tr[64];
#pragma unroll
  for (int i = 0; i < 16; ++i) {
    float4 v = *(const float4*)&trans[lane * 64 + 4 * i];
    tr[4 * i + 0] = v.x;
    tr[4 * i + 1] = v.y;
    tr[4 * i + 2] = v.z;
    tr[4 * i + 3] = v.w;
  }
  const int rec0 = m0;
  int t0 = rec0 - BURN;
  float fv;
  if (t0 <= 0) {
    t0 = 0;
    fv = (lane == STARTS) ? 0.0f : NEGV;  // true init -> exact
  } else {
    fv = 0.0f;  // washed out by burn-in (coalescence)
  }
  // burn-in: max only, 4 independent chains; spin per 16-row producer block
  for (int tb = t0; tb < rec0; tb += 16) {
    const int rb = tb >> 4;  // producer chunk id (< c)
    int spins = 0;
    while (__hip_atomic_load(&flags[rb], __ATOMIC_RELAXED,
                             __HIP_MEMORY_SCOPE_AGENT) == 0u) {
      __builtin_amdgcn_s_sleep(2);
      if (++spins > SPIN_BOUND) break;  // never hit in normal operation
    }
    __threadfence();  // acquire: invalidate stale cached feats
    for (int t = tb; t < tb + 16; ++t) {
      float feat = feats[t * 64 + lane];
      float q0 = -3.0e38f, q1 = -3.0e38f, q2 = -3.0e38f, q3 = -3.0e38f;
#pragma unroll
      for (int p = 0; p < 64; p += 4) {
        q0 = fmaxf(q0, lane_bcast(fv, p + 0) + tr[p + 0]);
        q1 = fmaxf(q1, lane_bcast(fv, p + 1) + tr[p + 1]);
        q2 = fmaxf(q2, lane_bcast(fv, p + 2) + tr[p + 2]);
        q3 = fmaxf(q3, lane_bcast(fv, p + 3) + tr[p + 3]);
      }
      float nf = fmaxf(fmaxf(q0, q1), fmaxf(q2, q3)) + feat;
      nf = nf - lane_bcast(nf, 0);  // renormalize (argmax-invariant)
      fv = nf;
    }
  }
  // recorded: grouped 4x16 ordered argmax (bit-identical to serial first-max:
  // contiguous ranges, strict > both in-group and at combine). feats from LDS.
  for (int t = rec0; t < rec0 + CHUNK_L; ++t) {
    float feat = fl[(t - rec0) * 64 + lane];
    float g0 = -3.0e38f, g1 = -3.0e38f, g2 = -3.0e38f, g3 = -3.0e38f;
    int b0 = 0, b1 = 16, b2 = 32, b3 = 48;
#pragma unroll
    for (int i = 0; i < 16; ++i) {
      float s0 = lane_bcast(fv, i) + tr[i];
      float s1 = lane_bcast(fv, i + 16) + tr[i + 16];
      float s2 = lane_bcast(fv, i + 32) + tr[i + 32];
      float s3 = lane_bcast(fv, i + 48) + tr[i + 48];
      if (s0 > g0) { g0 = s0; b0 = i; }
      if (s1 > g1) { g1 = s1; b1 = i + 16; }
      if (s2 > g2) { g2 = s2; b2 = i + 32; }
      if (s3 > g3) { g3 = s3; b3 = i + 48; }
    }
    float m = g0; int bi = b0;
    if (g1 > m) { m = g1; bi = b1; }
    if (g2 > m) { m = g2; bi = b2; }
    if (g3 > m) { m = g3; bi = b3; }
    bptr[t * 64 + lane] = (unsigned char)bi;
    float nf = m + feat;
    nf = nf - lane_bcast(nf, 0);
    if (t == T_FRAMES - 1) lastfv[lane] = nf;
    fv = nf;
  }
}

// ---------------------------------------------------------------------------
// K3+K4+K5 fused: compose -> arrive-counter barrier -> last block does the
// scan inline -> flag release -> decode (lb/sm stay resident in LDS, so the
// decode phase skips its reload + stage-1 recompute entirely).
// ---------------------------------------------------------------------------
__global__ __launch_bounds__(128) void backtrace_kernel(
    const unsigned char* __restrict__ bptr, const float* __restrict__ feats,
    const float* __restrict__ trans, const float* __restrict__ lastfv,
    unsigned char* __restrict__ map8, int* __restrict__ enter,
    unsigned int* __restrict__ cnt, unsigned int* __restrict__ flag2,
    float* __restrict__ out) {
  __shared__ unsigned char lb[BT_S * 64];
  __shared__ unsigned char sm[8 * 64];
  __shared__ unsigned char lm[BT_C * 64];
  __shared__ unsigned char sm2[8 * 64];
  __shared__ int endt[8];
  __shared__ unsigned char tl[BT_S];
  __shared__ double red[128];
  __shared__ int sh_last;
  __shared__ int sbest;
  const int c = blockIdx.x, tid = threadIdx.x;

  // ---- compose (K3): bptr chunk -> lb -> sm -> map8 ----
  {
    const uint4* src = (const uint4*)(bptr + (size_t)c * BT_S * 64);
    uint4* dst = (uint4*)lb;
    for (int i = tid; i < (BT_S * 64) / 16; i += 128) dst[i] = src[i];
  }
  __syncthreads();
  {
    const int st = tid & 63;
    const int sA = tid >> 6;  // 0..1
    int m0 = st, m1 = st, m2 = st, m3 = st;
#pragma unroll
    for (int i = 15; i >= 0; --i) {
      m0 = lb[((sA + 0) * 16 + i) * 64 + m0];
      m1 = lb[((sA + 2) * 16 + i) * 64 + m1];
      m2 = lb[((sA + 4) * 16 + i) * 64 + m2];
      m3 = lb[((sA + 6) * 16 + i) * 64 + m3];
    }
    sm[(sA + 0) * 64 + st] = (unsigned char)m0;
    sm[(sA + 2) * 64 + st] = (unsigned char)m1;
    sm[(sA + 4) * 64 + st] = (unsigned char)m2;
    sm[(sA + 6) * 64 + st] = (unsigned char)m3;
  }
  __syncthreads();
  if (tid < 64) {
    int m = tid;
#pragma unroll
    for (int s = 7; s >= 0; --s) m = sm[s * 64 + m];
    map8[c * 64 + tid] = (unsigned char)m;
  }
  __syncthreads();
  // ---- arrive ----
  if (tid == 0) {
    __threadfence();
    unsigned int old = atomicAdd(cnt, 1u);
    sh_last = (old == (unsigned)(BT_C - 1)) ? 1 : 0;
    if (sh_last) __threadfence();  // acquire all blocks' map8
  }
  __syncthreads();
  if (sh_last) {
    // ---- scan (K4) on the last-arriving block ----
    if (tid < 64) {  // wave 0: terminal argmax (shift-invariant)
      float v = lastfv[tid] + trans[STOPS * 64 + tid];
      float m = -3.0e38f;
      int bi = 0;
#pragma unroll
      for (int p = 0; p < 64; ++p) {
        float s = lane_bcast(v, p);
        if (s > m) { m = s; bi = p; }
      }
      if (tid == 0) sbest = bi;
    }
    {
      const uint4* src = (const uint4*)map8;
      uint4* dst = (uint4*)lm;
      for (int i = tid; i < (BT_C * 64) / 16; i += 128) dst[i] = src[i];
    }
    __syncthreads();
    {
      const int st = tid & 63;
      const int sA = tid >> 6;
      int m0 = st, m1 = st, m2 = st, m3 = st;
#pragma unroll
      for (int i = 15; i >= 0; --i) {
        m0 = lm[((sA + 0) * 16 + i) * 64 + m0];
        m1 = lm[((sA + 2) * 16 + i) * 64 + m1];
        m2 = lm[((sA + 4) * 16 + i) * 64 + m2];
        m3 = lm[((sA + 6) * 16 + i) * 64 + m3];
      }
      sm2[(sA + 0) * 64 + st] = (unsigned char)m0;
      sm2[(sA + 2) * 64 + st] = (unsigned char)m1;
      sm2[(sA + 4) * 64 + st] = (unsigned char)m2;
      sm2[(sA + 6) * 64 + st] = (unsigned char)m3;
    }
    __syncthreads();
    if (tid == 0) {
      int e = sbest;
      endt[7] = e;
      for (int s = 7; s >= 1; --s) { e = sm2[s * 64 + e]; endt[s - 1] = e; }
    }
    __syncthreads();
    if (tid < 8) {
      int e = endt[tid];
      for (int i = 15; i >= 0; --i) {
        int cc = tid * 16 + i;
        enter[cc] = e;
        e = lm[cc * 64 + e];
      }
    }
    if (tid == 127) out[0] = 0.0f;
    __syncthreads();
    if (tid == 0) {
      __threadfence();
      __hip_atomic_store(flag2, 1u, __ATOMIC_RELEASE, __HIP_MEMORY_SCOPE_AGENT);
    }
  } else {
    if (tid == 0) {
      int spins = 0;
      while (__hip_atomic_load(flag2, __ATOMIC_RELAXED,
                               __HIP_MEMORY_SCOPE_AGENT) == 0u) {
        __builtin_amdgcn_s_sleep(2);
        if (++spins > SPIN_BOUND) break;
      }
      __threadfence();
    }
  }
  __syncthreads();
  // ---- decode (K5) using resident lb/sm ----
  if (tid == 0) {
    int e = enter[c];
    endt[7] = e;
    for (int s = 7; s >= 1; --s) { e = sm[s * 64 + e]; endt[s - 1] = e; }
  }
  __syncthreads();
  if (tid < 8) {
    int e = endt[tid];
    for (int i = 15; i >= 0; --i) {
      tl[tid * 16 + i] = (unsigned char)e;
      e = lb[(tid * 16 + i) * 64 + e];
    }
  }
  __syncthreads();
  const int t = c * BT_S + tid;
  const int tg = tl[tid];
  out[1 + t] = (float)tg;
  double sc = (double)feats[(size_t)t * 64 + tg];
  int prev = (tid == 0) ? ((c == 0) ? STARTS : enter[c - 1]) : (int)tl[tid - 1];
  sc += (double)trans[tg * 64 + prev];
  if (t == T_FRAMES - 1) sc += (double)trans[STOPS * 64 + tg];
  red[tid] = sc;
  __syncthreads();
  for (int off = 64; off > 0; off >>= 1) {
    if (tid < off) red[tid] += red[tid + off];
    __syncthreads();
  }
  if (tid == 0) atomicAdd(&out[0], (float)red[0]);
}

// ---------------------------------------------------------------------------
extern "C" void kernel_launch(void* const* d_in, const int* in_sizes, int n_in,
                              void* d_out, int out_size, void* d_ws,
                              size_t ws_size, hipStream_t stream) {
  const float* video = (const float*)d_in[0];  // [16384, 4096]
  const float* W = (const float*)d_in[1];      // [64, 4096]
  const float* bias = (const float*)d_in[2];   // [64]
  const float* trans = (const float*)d_in[3];  // [64, 64]
  float* out = (float*)d_out;                  // [1 + 16384]

  char* ws = (char*)d_ws;
  float* feats = (float*)(ws);                             // 4 MB
  unsigned short* wbf = (unsigned short*)(ws + 0x400000);  // 512 KB
  unsigned char* bptr = (unsigned char*)(ws + 0x500000);   // 1 MB
  unsigned char* map8 = (unsigned char*)(ws + 0x600000);   // 8 KB
  int* enter = (int*)(ws + 0x602000);                      // 512 B
  float* lastfv = (float*)(ws + 0x603000);                 // 256 B
  unsigned int* flags = (unsigned int*)(ws + 0x604000);    // 1024+2 u32

  wconv_kernel<<<dim3(256), dim3(256), 0, stream>>>(W, wbf, flags);
  gemm_vit_kernel<<<dim3(NCHUNK), dim3(256), 0, stream>>>(
      video, wbf, bias, trans, feats, bptr, lastfv, flags);
  backtrace_kernel<<<dim3(BT_C), dim3(128), 0, stream>>>(
      bptr, feats, trans, lastfv, map8, enter, flags + NCHUNK,
      flags + NCHUNK + 1, out);
}

// Round 2
// 471.649 us; speedup vs baseline: 1.3275x; 1.3275x over previous
//
#include <hip/hip_runtime.h>

// Problem constants
#define T_FRAMES 16384
#define KDIM 4096
#define STARTS 62
#define STOPS 63
#define NEGV (-10000.0f)

// Chunked-Viterbi (max-plus coalescence: any init washes out up to an additive
// constant, argmax-invariant). Chunks whose burn-in would start at t<=0 run
// from the TRUE init -> exact. BURN=48 >> observed coalescence (<~30).
#define CHUNK_L 16
#define BURN 48
#define NCHUNK (T_FRAMES / CHUNK_L)   // 1024

// Backtrace chunking: 128 chunks x 128 steps.
#define BT_S 128
#define BT_C (T_FRAMES / BT_S)        // 128

#define SPIN_BOUND (1 << 20)

typedef __attribute__((ext_vector_type(8))) short s16x8;
typedef __attribute__((ext_vector_type(4))) float f32x4;

__device__ __forceinline__ float lane_bcast(float v, int l) {
  return __uint_as_float(__builtin_amdgcn_readlane(__float_as_uint(v), l));
}

// fp32 -> bf16 RTNE
__device__ __forceinline__ unsigned short f2bf(float f) {
  unsigned u = __float_as_uint(f);
  return (unsigned short)((u + 0x7FFFu + ((u >> 16) & 1u)) >> 16);
}

// ---------------------------------------------------------------------------
// K0: W fp32 [64][4096] -> bf16 (row-major); block 0 zeroes the 2 sync words
// used by the fused backtrace kernel (re-zeroed every graph replay).
// ---------------------------------------------------------------------------
__global__ __launch_bounds__(256) void wconv_kernel(
    const float* __restrict__ W, unsigned short* __restrict__ wbf,
    unsigned int* __restrict__ sync) {
  if (blockIdx.x == 0 && threadIdx.x < 2) sync[threadIdx.x] = 0u;
  int i = (blockIdx.x * 256 + threadIdx.x) * 4;
  float4 v = *(const float4*)&W[i];
  ushort4 o;
  o.x = f2bf(v.x); o.y = f2bf(v.y); o.z = f2bf(v.z); o.w = f2bf(v.w);
  *(ushort4*)&wbf[i] = o;
}

// ---------------------------------------------------------------------------
// K1: feats = relu(video @ W^T + b) via bf16 MFMA, K-split x4.
// 1024 blocks x 256 thr; block = 16 rows; wave w owns K in [w*1024,(w+1)*1024).
// A-frag loaded straight from global fp32 (32 B/lane, wave covers 16 full
// 128B lines per iter) and converted in-register; B-frag 16 B from bf16 W.
// LDS cross-wave reduction + bias + relu epilogue. ~HBM-bound (43 us floor).
// ---------------------------------------------------------------------------
__global__ __launch_bounds__(256, 4) void gemm_mfma_kernel(
    const float* __restrict__ video, const unsigned short* __restrict__ wbf,
    const float* __restrict__ bias, float* __restrict__ feats) {
  __shared__ float red[4 * 16 * 68];
  const int tid = threadIdx.x;
  const int wave = tid >> 6, lane = tid & 63;
  const int col = lane & 15, quad = lane >> 4;
  const int m0 = blockIdx.x * 16;

  const float* aptr = video + (size_t)(m0 + col) * KDIM + quad * 8;
  const unsigned short* bptr0 = wbf + (size_t)col * KDIM + quad * 8;

  f32x4 acc[4];
#pragma unroll
  for (int nt = 0; nt < 4; ++nt) acc[nt] = (f32x4){0.f, 0.f, 0.f, 0.f};

  const int kbase = wave * (KDIM / 4);
#pragma unroll 2
  for (int kc = kbase; kc < kbase + KDIM / 4; kc += 32) {
    float4 a0 = *(const float4*)(aptr + kc);
    float4 a1 = *(const float4*)(aptr + kc + 4);
    s16x8 bf[4];
#pragma unroll
    for (int nt = 0; nt < 4; ++nt)
      bf[nt] = *(const s16x8*)(bptr0 + (size_t)nt * 16 * KDIM + kc);
    s16x8 af;
    af[0] = (short)f2bf(a0.x); af[1] = (short)f2bf(a0.y);
    af[2] = (short)f2bf(a0.z); af[3] = (short)f2bf(a0.w);
    af[4] = (short)f2bf(a1.x); af[5] = (short)f2bf(a1.y);
    af[6] = (short)f2bf(a1.z); af[7] = (short)f2bf(a1.w);
#pragma unroll
    for (int nt = 0; nt < 4; ++nt)
      acc[nt] = __builtin_amdgcn_mfma_f32_16x16x32_bf16(af, bf[nt], acc[nt], 0, 0, 0);
  }

#pragma unroll
  for (int nt = 0; nt < 4; ++nt)
#pragma unroll
    for (int r = 0; r < 4; ++r) {
      int m = quad * 4 + r, n = nt * 16 + col;
      red[wave * 1088 + m * 68 + n] = acc[nt][r];
    }
  __syncthreads();
  {
    int m = tid >> 4, n = (tid & 15) * 4;
    float4 s = *(const float4*)&red[0 * 1088 + m * 68 + n];
    float4 s1 = *(const float4*)&red[1 * 1088 + m * 68 + n];
    float4 s2 = *(const float4*)&red[2 * 1088 + m * 68 + n];
    float4 s3 = *(const float4*)&red[3 * 1088 + m * 68 + n];
    float4 bb = *(const float4*)&bias[n];
    float4 r;
    r.x = fmaxf(s.x + s1.x + s2.x + s3.x + bb.x, 0.f);
    r.y = fmaxf(s.y + s1.y + s2.y + s3.y + bb.y, 0.f);
    r.z = fmaxf(s.z + s1.z + s2.z + s3.z + bb.z, 0.f);
    r.w = fmaxf(s.w + s1.w + s2.w + s3.w + bb.w, 0.f);
    *(float4*)&feats[(size_t)(m0 + m) * 64 + n] = r;
  }
}

// ---------------------------------------------------------------------------
// K2: fused Viterbi forward + backpointers. One wave per chunk; lane = next
// state. Burn-in: fast 4-chain max. Recorded steps: grouped 4x16 ordered
// argmax (bit-identical to serial first-max: contiguous ranges, strict >
// in-group and at combine in ascending group order). feats loads are
// software-pipelined one step ahead.
// ---------------------------------------------------------------------------
__global__ __launch_bounds__(64) void viterbi_fvbp_kernel(
    const float* __restrict__ feats, const float* __restrict__ trans,
    unsigned char* __restrict__ bptr, float* __restrict__ lastfv) {
  const int c = blockIdx.x;
  const int lane = threadIdx.x;
  float tr[64];
#pragma unroll
  for (int i = 0; i < 16; ++i) {
    float4 v = *(const float4*)&trans[lane * 64 + 4 * i];
    tr[4 * i + 0] = v.x;
    tr[4 * i + 1] = v.y;
    tr[4 * i + 2] = v.z;
    tr[4 * i + 3] = v.w;
  }
  const int rec0 = c * CHUNK_L;
  int t0 = rec0 - BURN;
  float fv;
  if (t0 <= 0) {
    t0 = 0;
    fv = (lane == STARTS) ? 0.0f : NEGV;  // true init -> exact
  } else {
    fv = 0.0f;  // washed out by burn-in (coalescence)
  }
  float feat_next = feats[t0 * 64 + lane];
  // burn-in: max only, 4 independent chains
  for (int t = t0; t < rec0; ++t) {
    float feat = feat_next;
    feat_next = feats[(t + 1) * 64 + lane];
    float m0 = -3.0e38f, m1 = -3.0e38f, m2 = -3.0e38f, m3 = -3.0e38f;
#pragma unroll
    for (int p = 0; p < 64; p += 4) {
      m0 = fmaxf(m0, lane_bcast(fv, p + 0) + tr[p + 0]);
      m1 = fmaxf(m1, lane_bcast(fv, p + 1) + tr[p + 1]);
      m2 = fmaxf(m2, lane_bcast(fv, p + 2) + tr[p + 2]);
      m3 = fmaxf(m3, lane_bcast(fv, p + 3) + tr[p + 3]);
    }
    float nf = fmaxf(fmaxf(m0, m1), fmaxf(m2, m3)) + feat;
    nf = nf - lane_bcast(nf, 0);  // renormalize (argmax-invariant)
    fv = nf;
  }
  // recorded: grouped 4x16 ordered argmax -> bptr
  for (int t = rec0; t < rec0 + CHUNK_L; ++t) {
    float feat = feat_next;
    if (t + 1 < T_FRAMES) feat_next = feats[(t + 1) * 64 + lane];
    float g0 = -3.0e38f, g1 = -3.0e38f, g2 = -3.0e38f, g3 = -3.0e38f;
    int b0 = 0, b1 = 16, b2 = 32, b3 = 48;
#pragma unroll
    for (int i = 0; i < 16; ++i) {
      float s0 = lane_bcast(fv, i) + tr[i];
      float s1 = lane_bcast(fv, i + 16) + tr[i + 16];
      float s2 = lane_bcast(fv, i + 32) + tr[i + 32];
      float s3 = lane_bcast(fv, i + 48) + tr[i + 48];
      if (s0 > g0) { g0 = s0; b0 = i; }
      if (s1 > g1) { g1 = s1; b1 = i + 16; }
      if (s2 > g2) { g2 = s2; b2 = i + 32; }
      if (s3 > g3) { g3 = s3; b3 = i + 48; }
    }
    float m = g0; int bi = b0;
    if (g1 > m) { m = g1; bi = b1; }
    if (g2 > m) { m = g2; bi = b2; }
    if (g3 > m) { m = g3; bi = b3; }
    bptr[t * 64 + lane] = (unsigned char)bi;
    float nf = m + feat;
    nf = nf - lane_bcast(nf, 0);
    if (t == T_FRAMES - 1) lastfv[lane] = nf;
    fv = nf;
  }
}

// ---------------------------------------------------------------------------
// K3+K4+K5 fused: compose -> arrive-counter barrier -> last block does the
// scan inline -> flag release -> decode (lb/sm stay resident in LDS, so the
// decode phase skips its reload + stage-1 recompute entirely). 128 blocks of
// 128 threads: trivially all co-resident, so the barrier is safe.
// ---------------------------------------------------------------------------
__global__ __launch_bounds__(128) void backtrace_kernel(
    const unsigned char* __restrict__ bptr, const float* __restrict__ feats,
    const float* __restrict__ trans, const float* __restrict__ lastfv,
    unsigned char* __restrict__ map8, int* __restrict__ enter,
    unsigned int* __restrict__ cnt, unsigned int* __restrict__ flag2,
    float* __restrict__ out) {
  __shared__ unsigned char lb[BT_S * 64];
  __shared__ unsigned char sm[8 * 64];
  __shared__ unsigned char lm[BT_C * 64];
  __shared__ unsigned char sm2[8 * 64];
  __shared__ int endt[8];
  __shared__ unsigned char tl[BT_S];
  __shared__ double red[128];
  __shared__ int sh_last;
  __shared__ int sbest;
  const int c = blockIdx.x, tid = threadIdx.x;

  // ---- compose (K3): bptr chunk -> lb -> sm -> map8 ----
  {
    const uint4* src = (const uint4*)(bptr + (size_t)c * BT_S * 64);
    uint4* dst = (uint4*)lb;
    for (int i = tid; i < (BT_S * 64) / 16; i += 128) dst[i] = src[i];
  }
  __syncthreads();
  {
    const int st = tid & 63;
    const int sA = tid >> 6;  // 0..1
    int m0 = st, m1 = st, m2 = st, m3 = st;
#pragma unroll
    for (int i = 15; i >= 0; --i) {
      m0 = lb[((sA + 0) * 16 + i) * 64 + m0];
      m1 = lb[((sA + 2) * 16 + i) * 64 + m1];
      m2 = lb[((sA + 4) * 16 + i) * 64 + m2];
      m3 = lb[((sA + 6) * 16 + i) * 64 + m3];
    }
    sm[(sA + 0) * 64 + st] = (unsigned char)m0;
    sm[(sA + 2) * 64 + st] = (unsigned char)m1;
    sm[(sA + 4) * 64 + st] = (unsigned char)m2;
    sm[(sA + 6) * 64 + st] = (unsigned char)m3;
  }
  __syncthreads();
  if (tid < 64) {
    int m = tid;
#pragma unroll
    for (int s = 7; s >= 0; --s) m = sm[s * 64 + m];
    map8[c * 64 + tid] = (unsigned char)m;
  }
  __syncthreads();
  // ---- arrive ----
  if (tid == 0) {
    __threadfence();
    unsigned int old = atomicAdd(cnt, 1u);
    sh_last = (old == (unsigned)(BT_C - 1)) ? 1 : 0;
    if (sh_last) __threadfence();  // acquire all blocks' map8
  }
  __syncthreads();
  if (sh_last) {
    // ---- scan (K4) on the last-arriving block ----
    if (tid < 64) {  // wave 0: terminal argmax (shift-invariant)
      float v = lastfv[tid] + trans[STOPS * 64 + tid];
      float m = -3.0e38f;
      int bi = 0;
#pragma unroll
      for (int p = 0; p < 64; ++p) {
        float s = lane_bcast(v, p);
        if (s > m) { m = s; bi = p; }
      }
      if (tid == 0) sbest = bi;
    }
    {
      const uint4* src = (const uint4*)map8;
      uint4* dst = (uint4*)lm;
      for (int i = tid; i < (BT_C * 64) / 16; i += 128) dst[i] = src[i];
    }
    __syncthreads();
    {
      const int st = tid & 63;
      const int sA = tid >> 6;
      int m0 = st, m1 = st, m2 = st, m3 = st;
#pragma unroll
      for (int i = 15; i >= 0; --i) {
        m0 = lm[((sA + 0) * 16 + i) * 64 + m0];
        m1 = lm[((sA + 2) * 16 + i) * 64 + m1];
        m2 = lm[((sA + 4) * 16 + i) * 64 + m2];
        m3 = lm[((sA + 6) * 16 + i) * 64 + m3];
      }
      sm2[(sA + 0) * 64 + st] = (unsigned char)m0;
      sm2[(sA + 2) * 64 + st] = (unsigned char)m1;
      sm2[(sA + 4) * 64 + st] = (unsigned char)m2;
      sm2[(sA + 6) * 64 + st] = (unsigned char)m3;
    }
    __syncthreads();
    if (tid == 0) {
      int e = sbest;
      endt[7] = e;
      for (int s = 7; s >= 1; --s) { e = sm2[s * 64 + e]; endt[s - 1] = e; }
    }
    __syncthreads();
    if (tid < 8) {
      int e = endt[tid];
      for (int i = 15; i >= 0; --i) {
        int cc = tid * 16 + i;
        enter[cc] = e;
        e = lm[cc * 64 + e];
      }
    }
    if (tid == 127) out[0] = 0.0f;
    __syncthreads();
    if (tid == 0) {
      __threadfence();
      __hip_atomic_store(flag2, 1u, __ATOMIC_RELEASE, __HIP_MEMORY_SCOPE_AGENT);
    }
  } else {
    if (tid == 0) {
      int spins = 0;
      while (__hip_atomic_load(flag2, __ATOMIC_RELAXED,
                               __HIP_MEMORY_SCOPE_AGENT) == 0u) {
        __builtin_amdgcn_s_sleep(2);
        if (++spins > SPIN_BOUND) break;
      }
      __threadfence();
    }
  }
  __syncthreads();
  // ---- decode (K5) using resident lb/sm ----
  if (tid == 0) {
    int e = enter[c];
    endt[7] = e;
    for (int s = 7; s >= 1; --s) { e = sm[s * 64 + e]; endt[s - 1] = e; }
  }
  __syncthreads();
  if (tid < 8) {
    int e = endt[tid];
    for (int i = 15; i >= 0; --i) {
      tl[tid * 16 + i] = (unsigned char)e;
      e = lb[(tid * 16 + i) * 64 + e];
    }
  }
  __syncthreads();
  const int t = c * BT_S + tid;
  const int tg = tl[tid];
  out[1 + t] = (float)tg;
  double sc = (double)feats[(size_t)t * 64 + tg];
  int prev = (tid == 0) ? ((c == 0) ? STARTS : enter[c - 1]) : (int)tl[tid - 1];
  sc += (double)trans[tg * 64 + prev];
  if (t == T_FRAMES - 1) sc += (double)trans[STOPS * 64 + tg];
  red[tid] = sc;
  __syncthreads();
  for (int off = 64; off > 0; off >>= 1) {
    if (tid < off) red[tid] += red[tid + off];
    __syncthreads();
  }
  if (tid == 0) atomicAdd(&out[0], (float)red[0]);
}

// ---------------------------------------------------------------------------
extern "C" void kernel_launch(void* const* d_in, const int* in_sizes, int n_in,
                              void* d_out, int out_size, void* d_ws,
                              size_t ws_size, hipStream_t stream) {
  const float* video = (const float*)d_in[0];  // [16384, 4096]
  const float* W = (const float*)d_in[1];      // [64, 4096]
  const float* bias = (const float*)d_in[2];   // [64]
  const float* trans = (const float*)d_in[3];  // [64, 64]
  float* out = (float*)d_out;                  // [1 + 16384]

  char* ws = (char*)d_ws;
  float* feats = (float*)(ws);                             // 4 MB
  unsigned short* wbf = (unsigned short*)(ws + 0x400000);  // 512 KB
  unsigned char* bptr = (unsigned char*)(ws + 0x500000);   // 1 MB
  unsigned char* map8 = (unsigned char*)(ws + 0x600000);   // 8 KB
  int* enter = (int*)(ws + 0x602000);                      // 512 B
  float* lastfv = (float*)(ws + 0x603000);                 // 256 B
  unsigned int* sync = (unsigned int*)(ws + 0x604000);     // 2 u32

  wconv_kernel<<<dim3(256), dim3(256), 0, stream>>>(W, wbf, sync);
  gemm_mfma_kernel<<<dim3(T_FRAMES / 16), dim3(256), 0, stream>>>(video, wbf, bias, feats);
  viterbi_fvbp_kernel<<<dim3(NCHUNK), dim3(64), 0, stream>>>(feats, trans, bptr, lastfv);
  backtrace_kernel<<<dim3(BT_C), dim3(128), 0, stream>>>(
      bptr, feats, trans, lastfv, map8, enter, sync, sync + 1, out);
}